// Round 18
// baseline (108.208 us; speedup 1.0000x reference)
//
#include <hip/hip_runtime.h>
#include <stdint.h>
#include <math.h>

// Problem shape (fixed by reference): xs [B,T,N,D] fp32, A [1,N,N] int32
#define BB 4
#define TT 32
#define NN 128
#define DD 32
#define NPB 16                       // nodes per block (16 nodes x 32 d = 512 threads)
#define TPB (NPB * DD)               // 512 threads
#define NBLK (BB * TT * (NN / NPB))  // 1024 blocks = exactly 4 per CU
#define CAP 16                       // band capacity; selected-bin overflow -> exact fallback
#define NK (CAP + 2)                 // 16 spatial slots + 2 temporal slots

// Arithmetic 8-bin partition of the value axis. ANY monotone non-decreasing
// bin function gives exact rank selection (equal values -> equal bins, so
// bins partition the multiset in value order). Median of ~66 N(0,1) lands in
// a bin with count <= CAP except ~1e-5/lane -> fallback is exact anyway.
__device__ __forceinline__ int bin8(float x) {
    int i = (int)fmaf(x, 5.0f, 4.0f);   // trunc; monotone non-decreasing
    i = i < 0 ? 0 : i;
    return i > 7 ? 7 : i;
}

// R18 = R17 (certified 55.3us) with the BOUNDED 8-wide-ILP fallback moved
// UNCHANGED into a __noinline__ cold function -- the clean version of R13's
// code-size experiment (R13 confounded outlining with an algorithm change
// to a serial mask-walk, creating 145us straggler waves; here the algorithm
// is byte-equivalent, so no straggler risk). Tests the last standing stall
// theory: instruction-fetch pressure from the ~50% of static code that is
// the cold fallback sitting in every wave's fetch stream. Pre-committed
// read: 47-52us => I-fetch was the stall; 54-57 flat => theory dead, all
// nameable stall mechanisms exhausted, write the plateau arithmetic.
__device__ __attribute__((noinline))
float fb_exact_scan(const float* sval, const uint8_t* nb, int d, int dg, int ne,
                    float exv0, float exv1, int k, uint32_t r, bool fb, float result) {
    const float INFV = __uint_as_float(0x7F800000u);
    bool done = !fb;
    for (int i0 = 0; __ballot(!done && i0 < k); i0 += 8) {
        float k8[8]; uint32_t c8[8];
        #pragma unroll
        for (int u = 0; u < 8; ++u) {
            int i = i0 + u;
            float sv = sval[nb[i & 127] * DD + d];
            float ev = ((i - dg) == 0) ? exv0 : exv1;
            float v = (i < dg) ? sv : ev;
            k8[u] = (i < k) ? v : INFV;
            c8[u] = 0;
        }
        for (int j = 0; j < dg; ++j) {
            float xv = sval[nb[j] * DD + d];
            #pragma unroll
            for (int u = 0; u < 8; ++u) c8[u] += (xv < k8[u]);
        }
        if (ne >= 1) {
            #pragma unroll
            for (int u = 0; u < 8; ++u) c8[u] += (exv0 < k8[u]);
        }
        if (ne == 2) {
            #pragma unroll
            for (int u = 0; u < 8; ++u) c8[u] += (exv1 < k8[u]);
        }
        #pragma unroll
        for (int u = 0; u < 8; ++u) {
            if (!done && (i0 + u) < k && c8[u] == r) { result = k8[u]; done = true; }
        }
    }
    if (__ballot(!done)) {  // duplicates across rank: exact multiset selection
        for (int i0 = 0; __ballot(!done && i0 < k); i0 += 4) {
            float k4[4]; uint32_t lt4[4], le4[4];
            #pragma unroll
            for (int u = 0; u < 4; ++u) {
                int i = i0 + u;
                float sv = sval[nb[i & 127] * DD + d];
                float ev = ((i - dg) == 0) ? exv0 : exv1;
                float v = (i < dg) ? sv : ev;
                k4[u] = (i < k) ? v : INFV;
                lt4[u] = 0; le4[u] = 0;
            }
            for (int j = 0; j < dg; ++j) {
                float xv = sval[nb[j] * DD + d];
                #pragma unroll
                for (int u = 0; u < 4; ++u) { lt4[u] += (xv < k4[u]); le4[u] += (xv <= k4[u]); }
            }
            if (ne >= 1) {
                #pragma unroll
                for (int u = 0; u < 4; ++u) { lt4[u] += (exv0 < k4[u]); le4[u] += (exv0 <= k4[u]); }
            }
            if (ne == 2) {
                #pragma unroll
                for (int u = 0; u < 4; ++u) { lt4[u] += (exv1 < k4[u]); le4[u] += (exv1 <= k4[u]); }
            }
            #pragma unroll
            for (int u = 0; u < 4; ++u) {
                if (!done && (i0 + u) < k && lt4[u] <= r && r < le4[u]) {
                    result = k4[u]; done = true;
                }
            }
        }
    }
    return result;
}

__global__ __launch_bounds__(TPB) void median_kernel(const float* __restrict__ xs,
                                                     const int* __restrict__ A,
                                                     float* __restrict__ out) {
    __shared__ __align__(16) float sval[NN * DD];       // 16 KB: current frame [n][d]
    __shared__ uint8_t sbin[NN * DD];                   // 4 KB: per-element bin (0..7)
    __shared__ __align__(16) uint32_t sbit[8 * DD * 4]; // 4 KB: bitplanes [bin][d][n/32]
    __shared__ uint32_t snbr_w[NPB * NN / 4];   // 2 KB: neighbor id lists (u8, fallback only)
    __shared__ __align__(16) uint32_t smask[NPB][4];    // 256 B: adjacency masks
    __shared__ int sdeg[NPB];

    const int tid = threadIdx.x;
    // Bijective XCD swizzle (NBLK % 8 == 0): each XCD gets a contiguous chunk
    // of 128 logical blocks = 16 whole frames -> frame re-reads are L2-local.
    const int bid = blockIdx.x;
    const int g = ((bid & 7) << 7) | (bid >> 3);
    const int ng = g & (NN / NPB - 1);       // % 8
    const int t  = (g >> 3) & (TT - 1);      // /8 % 32
    const int b  = g >> 8;                   // /256
    const int n0 = ng * NPB;

    const int d = tid & (DD - 1);
    const int nl = tid >> 5;  // local node 0..15
    const int n = n0 + nl;
    const int pv = (t > 0) ? 1 : 0;        // wave-uniform
    const int nv = (t < TT - 1) ? 1 : 0;   // wave-uniform
    const int ne = pv + nv;

    // temporal candidates as floats (coalesced; issued before the barrier)
    float exv0 = 0.0f, exv1 = 0.0f;
    if (pv) exv0 = xs[(((size_t)(b * TT + t - 1) * NN) + n) * DD + d];
    if (nv) {
        float v = xs[(((size_t)(b * TT + t + 1) * NN) + n) * DD + d];
        if (pv) exv1 = v; else exv0 = v;
    }

    // stage current frame (float4 coalesced) + per-element bins (u32-packed)
    const float4* src4 = (const float4*)(xs + ((size_t)(b * TT + t) * NN) * DD);
    #pragma unroll
    for (int s = 0; s < 2; ++s) {
        int i4 = tid + (s << 9);
        float4 f = src4[i4];
        ((float4*)sval)[i4] = f;
        uint32_t pk = (uint32_t)bin8(f.x) | ((uint32_t)bin8(f.y) << 8)
                    | ((uint32_t)bin8(f.z) << 16) | ((uint32_t)bin8(f.w) << 24);
        ((uint32_t*)sbin)[i4] = pk;
    }

    // ---- fused adjacency build: wave wid ballots rows 2*wid, 2*wid+1 of A
    // (+ implicit self loop) into compacted u8 lists AND raw mask words.
    {
        uint8_t* snbr = (uint8_t*)snbr_w;
        const int lane = tid & 63;
        const int wid = tid >> 6;  // 0..7
        const unsigned long long lmask = (1ULL << lane) - 1ULL;
        #pragma unroll
        for (int h = 0; h < 2; ++h) {
            const int rr = wid * 2 + h;          // local row 0..15
            const int nrow = n0 + rr;            // global node id
            const int* arow = A + nrow * NN;
            const bool b0 = (arow[lane] != 0) || (lane == nrow);
            const bool b1 = (arow[lane + 64] != 0) || (lane + 64 == nrow);
            const unsigned long long m0 = __ballot(b0);
            const unsigned long long m1 = __ballot(b1);
            const int c0 = __popcll(m0);
            if (b0) snbr[rr * NN + __popcll(m0 & lmask)] = (uint8_t)lane;
            if (b1) snbr[rr * NN + c0 + __popcll(m1 & lmask)] = (uint8_t)(lane + 64);
            if (lane == 0) {
                sdeg[rr] = c0 + __popcll(m1);
                smask[rr][0] = (uint32_t)m0;
                smask[rr][1] = (uint32_t)(m0 >> 32);
                smask[rr][2] = (uint32_t)m1;
                smask[rr][3] = (uint32_t)(m1 >> 32);
            }
        }
    }
    __syncthreads();  // sval/sbin/snbr/smask ready

    // ---- ownership bitplane build (sbin indirection: R15 A/B showed it
    // beats direct-f32 by 8us): thread (rep, wo, dd) owns 2 words; 32 sbin
    // byte reads (same-word broadcast -> ~free), regs, 2 stores. ----
    {
        const int rep = tid >> 7;        // 0..3 -> bins {2r, 2r+1}
        const int wo  = (tid >> 5) & 3;  // word 0..3 -> nodes [wo*32, wo*32+32)
        const int dd  = tid & 31;
        const int ba = rep * 2, bc = ba + 1;
        uint32_t lo = 0u, hi = 0u;
        #pragma unroll 8
        for (int q = 0; q < 32; ++q) {
            const int bv = (int)sbin[(wo * 32 + q) * DD + dd];
            lo |= (bv == ba) ? (1u << q) : 0u;
            hi |= (bv == bc) ? (1u << q) : 0u;
        }
        sbit[ba * 128 + dd * 4 + wo] = lo;
        sbit[bc * 128 + dd * 4 + wo] = hi;
    }
    __syncthreads();  // bitplanes visible

    const int dg = sdeg[nl];
    const int k = dg + ne;
    const uint32_t r = (uint32_t)((k - 1) >> 1);  // lower-median rank (0-based)
    const uint8_t* nb = (const uint8_t*)snbr_w + nl * NN;
    const float INFV = __uint_as_float(0x7F800000u);
    const int be0 = bin8(exv0);
    const int be1 = bin8(exv1);

    // ---- A1: bitplane histogram -- 8 x (b128 read, AND, popcount) ----
    const uint4 am4 = *((const uint4*)smask[nl]);  // broadcast within node-group
    int hist[8];
    const uint4* sbit4 = (const uint4*)sbit;
    #pragma unroll
    for (int bb = 0; bb < 8; ++bb) {
        uint4 w = sbit4[bb * 32 + d];
        hist[bb] = __popc(w.x & am4.x) + __popc(w.y & am4.y)
                 + __popc(w.z & am4.z) + __popc(w.w & am4.w);
    }

    // ---- prefix over bins (temporal folded in); select bin containing r ----
    uint32_t cum = 0, lowcnt = 0, mexp = 0;
    int selbin = -1;
    #pragma unroll
    for (int bb = 0; bb < 8; ++bb) {
        uint32_t bc = (uint32_t)hist[bb] + ((ne >= 1 && be0 == bb) ? 1u : 0u)
                                         + ((ne == 2 && be1 == bb) ? 1u : 0u);
        uint32_t nc = cum + bc;
        if (selbin < 0 && r < nc) { selbin = bb; lowcnt = cum; mexp = bc; }
        cum = nc;
    }
    const bool fb = (mexp > CAP);   // band too big -> exact fallback (~1e-5)
    const uint32_t rp = r - lowcnt; // rank within band

    // ---- A2: static ffs-walk of the band bitmask -> id register array ----
    const uint4 wsel = sbit4[selbin * 32 + d];   // selbin always in 0..7
    unsigned long long bm0 = (((unsigned long long)(wsel.y & am4.y)) << 32) | (wsel.x & am4.x);
    unsigned long long bm1 = (((unsigned long long)(wsel.w & am4.w)) << 32) | (wsel.z & am4.z);
    const int mc_sp = fb ? 0 : (__popcll(bm0) + __popcll(bm1));
    int ids[CAP];
    #pragma unroll
    for (int u = 0; u < CAP; ++u) {
        const bool lo = (bm0 != 0ull);
        const unsigned long long mm_ = lo ? bm0 : bm1;
        const int ff = __ffsll(mm_) - 1;  // -1 when empty
        ids[u] = (lo ? ff : 64 + ff) & 127;                   // in-bounds always
        const unsigned long long cl = mm_ & (mm_ - 1ull);
        bm0 = lo ? cl : bm0;
        bm1 = lo ? bm1 : cl;
    }

    // ---- gather band values: 16 independent sval reads, bank == d for ANY
    // id (addr = id*32+d) -> conflict-free by construction ----
    float ki[NK];
    #pragma unroll
    for (int u = 0; u < CAP; ++u)
        ki[u] = (u < mc_sp) ? sval[ids[u] * DD + d] : INFV;
    const bool t0 = (ne >= 1) && (be0 == selbin) && !fb;
    const bool t1 = (ne == 2) && (be1 == selbin) && !fb;
    ki[CAP]     = t0 ? exv0 : INFV;
    ki[CAP + 1] = t1 ? exv1 : INFV;

    // ---- rank within band: Batcher odd-even sorting network on 18 slots.
    // INF padding sorts high; valid count = mexp > rp (when !fb), so
    // sorted[rp] is exactly the multiset lower median. All indices are
    // compile-time constants after unroll -> ki[] stays in registers. ----
    #pragma unroll
    for (int p = 1; p < NK; p <<= 1) {
        #pragma unroll
        for (int kk = p; kk >= 1; kk >>= 1) {
            #pragma unroll
            for (int j = kk % p; j + kk < NK; j += 2 * kk) {
                #pragma unroll
                for (int i = 0; i < kk; ++i) {
                    const int a = i + j, c = i + j + kk;
                    if (c < NK && (a / (2 * p)) == (c / (2 * p))) {
                        const float lo_ = fminf(ki[a], ki[c]);
                        const float hi_ = fmaxf(ki[a], ki[c]);
                        ki[a] = lo_; ki[c] = hi_;
                    }
                }
            }
        }
    }
    float result = ki[0];
    #pragma unroll
    for (int u = 1; u < NK; ++u) result = (rp == (uint32_t)u) ? ki[u] : result;

    // ---- cold fallback (band > CAP; ~1e-5 of lanes): identical bounded
    // 8-wide-ILP scan, outlined to remove it from the hot fetch stream ----
    if (__ballot(fb)) {
        result = fb_exact_scan(sval, nb, d, dg, ne, exv0, exv1, k, r, fb, result);
    }

    out[(((size_t)(b * TT + t) * NN) + n) * DD + d] = result;
}

extern "C" void kernel_launch(void* const* d_in, const int* in_sizes, int n_in,
                              void* d_out, int out_size, void* d_ws, size_t ws_size,
                              hipStream_t stream) {
    const float* xs = (const float*)d_in[0];
    const int* A = (const int*)d_in[1];
    float* out = (float*)d_out;
    (void)d_ws; (void)ws_size;  // no workspace: adjacency fused into the kernel

    median_kernel<<<NBLK, TPB, 0, stream>>>(xs, A, out);
}

// Round 19
// 106.936 us; speedup vs baseline: 1.0119x; 1.0119x over previous
//
#include <hip/hip_runtime.h>
#include <stdint.h>
#include <math.h>

// Problem shape (fixed by reference): xs [B,T,N,D] fp32, A [1,N,N] int32
#define BB 4
#define TT 32
#define NN 128
#define DD 32
#define NPB 16                       // nodes per block (16 nodes x 32 d = 512 threads)
#define TPB (NPB * DD)               // 512 threads
#define NBLK (BB * TT * (NN / NPB))  // 1024 blocks = exactly 4 per CU
#define CAP 16                       // band capacity; selected-bin overflow -> exact fallback
#define NK (CAP + 2)                 // 16 spatial slots + 2 temporal slots

// Arithmetic 8-bin partition of the value axis. ANY monotone non-decreasing
// bin function gives exact rank selection (equal values -> equal bins, so
// bins partition the multiset in value order). Median of ~66 N(0,1) lands in
// a bin with count <= CAP except ~1e-5/lane -> fallback is exact anyway.
__device__ __forceinline__ int bin8(float x) {
    int i = (int)fmaf(x, 5.0f, 4.0f);   // trunc; monotone non-decreasing
    i = i < 0 ? 0 : i;
    return i > 7 ? 7 : i;
}

// R19 = R17 revert (certified best: 55.3us dispatch, VGPR 28). R18's
// outlined fallback REGRESSED (63.6us, VGPR 28->44, SGPR 64->96: call-ABI
// overhead poisons hot-path regalloc) -- I-fetch theory dead both ways
// (R13: outline+algo-change, R18: outline-only; both worse). PLATEAU
// ARITHMETIC: VALU issue 14.4us/SIMD (26%), LDS pipe ~6us, HBM 0.8%,
// conflicts 0 -- no throughput resource saturated; tested-flat: LDS size,
// block shape, wave count, swizzle; tested-negative: fewer waves, serial
// cold paths, outlining; VALU/LDS-op cuts now bounded <3us by issue math.
// Residual ~38us = dependent-chain latency (ffs-walk 16 serial steps,
// ~13-level sort net, prefix chain) x 4 block-generations/CU that TLP
// does not hide. Session dispatch: 74.7 -> 65 -> 58.4 -> 55.3us.
__global__ __launch_bounds__(TPB) void median_kernel(const float* __restrict__ xs,
                                                     const int* __restrict__ A,
                                                     float* __restrict__ out) {
    __shared__ __align__(16) float sval[NN * DD];       // 16 KB: current frame [n][d]
    __shared__ uint8_t sbin[NN * DD];                   // 4 KB: per-element bin (0..7)
    __shared__ __align__(16) uint32_t sbit[8 * DD * 4]; // 4 KB: bitplanes [bin][d][n/32]
    __shared__ uint32_t snbr_w[NPB * NN / 4];   // 2 KB: neighbor id lists (u8, fallback only)
    __shared__ __align__(16) uint32_t smask[NPB][4];    // 256 B: adjacency masks
    __shared__ int sdeg[NPB];

    const int tid = threadIdx.x;
    // Bijective XCD swizzle (NBLK % 8 == 0): each XCD gets a contiguous chunk
    // of 128 logical blocks = 16 whole frames -> frame re-reads are L2-local.
    const int bid = blockIdx.x;
    const int g = ((bid & 7) << 7) | (bid >> 3);
    const int ng = g & (NN / NPB - 1);       // % 8
    const int t  = (g >> 3) & (TT - 1);      // /8 % 32
    const int b  = g >> 8;                   // /256
    const int n0 = ng * NPB;

    const int d = tid & (DD - 1);
    const int nl = tid >> 5;  // local node 0..15
    const int n = n0 + nl;
    const int pv = (t > 0) ? 1 : 0;        // wave-uniform
    const int nv = (t < TT - 1) ? 1 : 0;   // wave-uniform
    const int ne = pv + nv;

    // temporal candidates as floats (coalesced; issued before the barrier)
    float exv0 = 0.0f, exv1 = 0.0f;
    if (pv) exv0 = xs[(((size_t)(b * TT + t - 1) * NN) + n) * DD + d];
    if (nv) {
        float v = xs[(((size_t)(b * TT + t + 1) * NN) + n) * DD + d];
        if (pv) exv1 = v; else exv0 = v;
    }

    // stage current frame (float4 coalesced) + per-element bins (u32-packed)
    const float4* src4 = (const float4*)(xs + ((size_t)(b * TT + t) * NN) * DD);
    #pragma unroll
    for (int s = 0; s < 2; ++s) {
        int i4 = tid + (s << 9);
        float4 f = src4[i4];
        ((float4*)sval)[i4] = f;
        uint32_t pk = (uint32_t)bin8(f.x) | ((uint32_t)bin8(f.y) << 8)
                    | ((uint32_t)bin8(f.z) << 16) | ((uint32_t)bin8(f.w) << 24);
        ((uint32_t*)sbin)[i4] = pk;
    }

    // ---- fused adjacency build: wave wid ballots rows 2*wid, 2*wid+1 of A
    // (+ implicit self loop) into compacted u8 lists AND raw mask words.
    {
        uint8_t* snbr = (uint8_t*)snbr_w;
        const int lane = tid & 63;
        const int wid = tid >> 6;  // 0..7
        const unsigned long long lmask = (1ULL << lane) - 1ULL;
        #pragma unroll
        for (int h = 0; h < 2; ++h) {
            const int rr = wid * 2 + h;          // local row 0..15
            const int nrow = n0 + rr;            // global node id
            const int* arow = A + nrow * NN;
            const bool b0 = (arow[lane] != 0) || (lane == nrow);
            const bool b1 = (arow[lane + 64] != 0) || (lane + 64 == nrow);
            const unsigned long long m0 = __ballot(b0);
            const unsigned long long m1 = __ballot(b1);
            const int c0 = __popcll(m0);
            if (b0) snbr[rr * NN + __popcll(m0 & lmask)] = (uint8_t)lane;
            if (b1) snbr[rr * NN + c0 + __popcll(m1 & lmask)] = (uint8_t)(lane + 64);
            if (lane == 0) {
                sdeg[rr] = c0 + __popcll(m1);
                smask[rr][0] = (uint32_t)m0;
                smask[rr][1] = (uint32_t)(m0 >> 32);
                smask[rr][2] = (uint32_t)m1;
                smask[rr][3] = (uint32_t)(m1 >> 32);
            }
        }
    }
    __syncthreads();  // sval/sbin/snbr/smask ready

    // ---- ownership bitplane build (sbin indirection: R15 A/B showed it
    // beats direct-f32 by 8us): thread (rep, wo, dd) owns 2 words; 32 sbin
    // byte reads (same-word broadcast -> ~free), regs, 2 stores. ----
    {
        const int rep = tid >> 7;        // 0..3 -> bins {2r, 2r+1}
        const int wo  = (tid >> 5) & 3;  // word 0..3 -> nodes [wo*32, wo*32+32)
        const int dd  = tid & 31;
        const int ba = rep * 2, bc = ba + 1;
        uint32_t lo = 0u, hi = 0u;
        #pragma unroll 8
        for (int q = 0; q < 32; ++q) {
            const int bv = (int)sbin[(wo * 32 + q) * DD + dd];
            lo |= (bv == ba) ? (1u << q) : 0u;
            hi |= (bv == bc) ? (1u << q) : 0u;
        }
        sbit[ba * 128 + dd * 4 + wo] = lo;
        sbit[bc * 128 + dd * 4 + wo] = hi;
    }
    __syncthreads();  // bitplanes visible

    const int dg = sdeg[nl];
    const int k = dg + ne;
    const uint32_t r = (uint32_t)((k - 1) >> 1);  // lower-median rank (0-based)
    const uint8_t* nb = (const uint8_t*)snbr_w + nl * NN;
    const float INFV = __uint_as_float(0x7F800000u);
    const int be0 = bin8(exv0);
    const int be1 = bin8(exv1);

    // ---- A1: bitplane histogram -- 8 x (b128 read, AND, popcount) ----
    const uint4 am4 = *((const uint4*)smask[nl]);  // broadcast within node-group
    int hist[8];
    const uint4* sbit4 = (const uint4*)sbit;
    #pragma unroll
    for (int bb = 0; bb < 8; ++bb) {
        uint4 w = sbit4[bb * 32 + d];
        hist[bb] = __popc(w.x & am4.x) + __popc(w.y & am4.y)
                 + __popc(w.z & am4.z) + __popc(w.w & am4.w);
    }

    // ---- prefix over bins (temporal folded in); select bin containing r ----
    uint32_t cum = 0, lowcnt = 0, mexp = 0;
    int selbin = -1;
    #pragma unroll
    for (int bb = 0; bb < 8; ++bb) {
        uint32_t bc = (uint32_t)hist[bb] + ((ne >= 1 && be0 == bb) ? 1u : 0u)
                                         + ((ne == 2 && be1 == bb) ? 1u : 0u);
        uint32_t nc = cum + bc;
        if (selbin < 0 && r < nc) { selbin = bb; lowcnt = cum; mexp = bc; }
        cum = nc;
    }
    const bool fb = (mexp > CAP);   // band too big -> exact fallback (~1e-5)
    const uint32_t rp = r - lowcnt; // rank within band

    // ---- A2: static ffs-walk of the band bitmask -> id register array ----
    const uint4 wsel = sbit4[selbin * 32 + d];   // selbin always in 0..7
    unsigned long long bm0 = (((unsigned long long)(wsel.y & am4.y)) << 32) | (wsel.x & am4.x);
    unsigned long long bm1 = (((unsigned long long)(wsel.w & am4.w)) << 32) | (wsel.z & am4.z);
    const int mc_sp = fb ? 0 : (__popcll(bm0) + __popcll(bm1));
    int ids[CAP];
    #pragma unroll
    for (int u = 0; u < CAP; ++u) {
        const bool lo = (bm0 != 0ull);
        const unsigned long long mm_ = lo ? bm0 : bm1;
        const int ff = __ffsll(mm_) - 1;  // -1 when empty
        ids[u] = (lo ? ff : 64 + ff) & 127;                   // in-bounds always
        const unsigned long long cl = mm_ & (mm_ - 1ull);
        bm0 = lo ? cl : bm0;
        bm1 = lo ? bm1 : cl;
    }

    // ---- gather band values: 16 independent sval reads, bank == d for ANY
    // id (addr = id*32+d) -> conflict-free by construction ----
    float ki[NK];
    #pragma unroll
    for (int u = 0; u < CAP; ++u)
        ki[u] = (u < mc_sp) ? sval[ids[u] * DD + d] : INFV;
    const bool t0 = (ne >= 1) && (be0 == selbin) && !fb;
    const bool t1 = (ne == 2) && (be1 == selbin) && !fb;
    ki[CAP]     = t0 ? exv0 : INFV;
    ki[CAP + 1] = t1 ? exv1 : INFV;

    // ---- rank within band: Batcher odd-even sorting network on 18 slots.
    // INF padding sorts high; valid count = mexp > rp (when !fb), so
    // sorted[rp] is exactly the multiset lower median. All indices are
    // compile-time constants after unroll -> ki[] stays in registers. ----
    #pragma unroll
    for (int p = 1; p < NK; p <<= 1) {
        #pragma unroll
        for (int kk = p; kk >= 1; kk >>= 1) {
            #pragma unroll
            for (int j = kk % p; j + kk < NK; j += 2 * kk) {
                #pragma unroll
                for (int i = 0; i < kk; ++i) {
                    const int a = i + j, c = i + j + kk;
                    if (c < NK && (a / (2 * p)) == (c / (2 * p))) {
                        const float lo_ = fminf(ki[a], ki[c]);
                        const float hi_ = fmaxf(ki[a], ki[c]);
                        ki[a] = lo_; ki[c] = hi_;
                    }
                }
            }
        }
    }
    float result = ki[0];
    #pragma unroll
    for (int u = 1; u < NK; ++u) result = (rp == (uint32_t)u) ? ki[u] : result;

    // ---- full fallback (band > CAP; ~1e-5 of lanes): BOUNDED 8-wide-ILP
    // exact scan over all k, INLINED (outlining regresses: R18; serial
    // mask-walks create straggler tails: R13) ----
    if (__ballot(fb)) {
        bool done = !fb;
        for (int i0 = 0; __ballot(!done && i0 < k); i0 += 8) {
            float k8[8]; uint32_t c8[8];
            #pragma unroll
            for (int u = 0; u < 8; ++u) {
                int i = i0 + u;
                float sv = sval[nb[i & 127] * DD + d];
                float ev = ((i - dg) == 0) ? exv0 : exv1;
                float v = (i < dg) ? sv : ev;
                k8[u] = (i < k) ? v : INFV;
                c8[u] = 0;
            }
            for (int j = 0; j < dg; ++j) {
                float xv = sval[nb[j] * DD + d];
                #pragma unroll
                for (int u = 0; u < 8; ++u) c8[u] += (xv < k8[u]);
            }
            if (ne >= 1) {
                #pragma unroll
                for (int u = 0; u < 8; ++u) c8[u] += (exv0 < k8[u]);
            }
            if (ne == 2) {
                #pragma unroll
                for (int u = 0; u < 8; ++u) c8[u] += (exv1 < k8[u]);
            }
            #pragma unroll
            for (int u = 0; u < 8; ++u) {
                if (!done && (i0 + u) < k && c8[u] == r) { result = k8[u]; done = true; }
            }
        }
        if (__ballot(!done)) {  // duplicates across rank: exact multiset selection
            for (int i0 = 0; __ballot(!done && i0 < k); i0 += 4) {
                float k4[4]; uint32_t lt4[4], le4[4];
                #pragma unroll
                for (int u = 0; u < 4; ++u) {
                    int i = i0 + u;
                    float sv = sval[nb[i & 127] * DD + d];
                    float ev = ((i - dg) == 0) ? exv0 : exv1;
                    float v = (i < dg) ? sv : ev;
                    k4[u] = (i < k) ? v : INFV;
                    lt4[u] = 0; le4[u] = 0;
                }
                for (int j = 0; j < dg; ++j) {
                    float xv = sval[nb[j] * DD + d];
                    #pragma unroll
                    for (int u = 0; u < 4; ++u) { lt4[u] += (xv < k4[u]); le4[u] += (xv <= k4[u]); }
                }
                if (ne >= 1) {
                    #pragma unroll
                    for (int u = 0; u < 4; ++u) { lt4[u] += (exv0 < k4[u]); le4[u] += (exv0 <= k4[u]); }
                }
                if (ne == 2) {
                    #pragma unroll
                    for (int u = 0; u < 4; ++u) { lt4[u] += (exv1 < k4[u]); le4[u] += (exv1 <= k4[u]); }
                }
                #pragma unroll
                for (int u = 0; u < 4; ++u) {
                    if (!done && (i0 + u) < k && lt4[u] <= r && r < le4[u]) {
                        result = k4[u]; done = true;
                    }
                }
            }
        }
    }

    out[(((size_t)(b * TT + t) * NN) + n) * DD + d] = result;
}

extern "C" void kernel_launch(void* const* d_in, const int* in_sizes, int n_in,
                              void* d_out, int out_size, void* d_ws, size_t ws_size,
                              hipStream_t stream) {
    const float* xs = (const float*)d_in[0];
    const int* A = (const int*)d_in[1];
    float* out = (float*)d_out;
    (void)d_ws; (void)ws_size;  // no workspace: adjacency fused into the kernel

    median_kernel<<<NBLK, TPB, 0, stream>>>(xs, A, out);
}